// Round 6
// baseline (81.012 us; speedup 1.0000x reference)
//
#include <hip/hip_runtime.h>
#include <hip/hip_bf16.h>
#include <float.h>

// x: [B=32][C=3][L=8192] f32, weight: [O=128][C=3][K=64] f32
// out[b][o] = -2 * max_t ( conv(b,o,t) - ||w_o||^2/2 - ||win_{b,t}||^2/2 ), t in [0, 8129)
#define BB 32
#define LL 8192
#define OO 128
#define KK 64
#define WW (LL - KK + 1)   // 8129
#define TCX 16             // 16 tcx * 4 waves * 128 t = 8192 t covered

typedef __attribute__((ext_vector_type(8))) short short8;
typedef __attribute__((ext_vector_type(4))) float f32x4;

union AB { int4 i4; int i[4]; short8 v; };

static __device__ __forceinline__ unsigned int pkbf(float a, float b) {
    union { __hip_bfloat162 h; unsigned int u; } cv;
    cv.h = __float22bfloat162_rn(make_float2(a, b));   // lo = a, hi = b -> v_cvt_pk_bf16_f32
    return cv.u;
}

// ---- prep: W -> bf16 swizzled [4 ob][24 rr][32 o2] 16B chunks; wn; out-init ----
// chunk (ob, rr=ks*4+qp, o2) holds w[ob*32+o2][c*64+h*32+qp*8 .. +8) bf16, ks=2c+h.
__global__ __launch_bounds__(256) void prep_kernel(const float* __restrict__ w,
                                                   unsigned short* __restrict__ wswz,
                                                   float* __restrict__ wn,
                                                   float* __restrict__ out) {
    int g = blockIdx.x * 256 + threadIdx.x;
    if (g < 3072) {
        int ob = g / 768;
        int rem = g - ob * 768;
        int rr = rem >> 5, o2 = rem & 31;
        int ks = rr >> 2, qp = rr & 3;
        int c = ks >> 1, h = ks & 1;
        const float* p = w + (size_t)(ob * 32 + o2) * 192 + c * 64 + h * 32 + qp * 8;
        float4 v0 = *(const float4*)p, v1 = *(const float4*)(p + 4);
        int4 pk;
        pk.x = (int)pkbf(v0.x, v0.y);
        pk.y = (int)pkbf(v0.z, v0.w);
        pk.z = (int)pkbf(v1.x, v1.y);
        pk.w = (int)pkbf(v1.z, v1.w);
        ((int4*)wswz)[g] = pk;
    }
    int oo = g - 3072;
    if (oo >= 0 && oo < OO) {
        const float* p = w + oo * 192;
        float s = 0.f;
        for (int i = 0; i < 192; ++i) { float v = p[i]; s = fmaf(v, v, s); }
        wn[oo] = 0.5f * s;
    }
    int oi = g - 3200;
    if (oi >= 0 && oi < BB * OO) out[oi] = 3.389e38f;   // +inf-ish for atomicMin
}

// ---- main: grid (16 tcx, 4 ob, 32 b) = 2048 blocks, 4 FREE-RUNNING waves ----
// Wave wv owns one job: o in [32ob, 32ob+32), t in [T0w, T0w+128), T0w =
// (tcx*4+wv)*128. Private x/sq/P LDS slice per wave -> ONE barrier total (W).
__global__ __launch_bounds__(256, 4) void shapeconv_main(const float* __restrict__ x,
                                                         const unsigned short* __restrict__ wswz,
                                                         const float* __restrict__ wn,
                                                         float* __restrict__ out) {
    __shared__ __align__(16) unsigned short w_lds[6144];       // 12288 B (32 o)
    __shared__ __align__(16) unsigned short xw_lds[4][576];    // per-wave bf16 [3][192]
    __shared__ __align__(16) float sq_lds[4][192];
    __shared__ __align__(16) float P_lds[4][24];

    const int tcx = blockIdx.x;
    const int ob = blockIdx.y;     // 0..3 (32 o's per block)
    const int b  = blockIdx.z;
    const int tid = threadIdx.x;
    const int wv = tid >> 6;
    const int lane = tid & 63;
    const int n  = lane & 15;
    const int qp = lane >> 4;
    const int T0w = (tcx * 4 + wv) * 128;    // <= 8064

    // per-wave x loads issue first (latency hides under W DMA + pack)
    float2 va[3], vb[3];
    const float* xb = x + (size_t)b * 3 * LL;
    {
        int e0 = T0w + 2 * lane;             // max 8190: always in-bounds
        #pragma unroll
        for (int c = 0; c < 3; ++c) va[c] = *(const float2*)(xb + c * LL + e0);
        #pragma unroll
        for (int c = 0; c < 3; ++c) vb[c] = make_float2(0.f, 0.f);
        int e1 = T0w + 128 + 2 * lane;       // halo, lanes<32
        if (lane < 32 && e1 < LL) {
            #pragma unroll
            for (int c = 0; c < 3; ++c) vb[c] = *(const float2*)(xb + c * LL + e1);
        }
    }

    // W stage: 12288 B async global->LDS, width 16, linear layout
    {
        const char* src = (const char*)wswz + (size_t)ob * 12288 + tid * 16;
        #pragma unroll
        for (int i = 0; i < 3; ++i) {
            __builtin_amdgcn_global_load_lds(
                (const __attribute__((address_space(1))) unsigned int*)(src + i * 4096),
                (__attribute__((address_space(3))) unsigned int*)((char*)w_lds + tid * 16 + i * 4096),
                16, 0, 0);
        }
    }

    // shapelet half-norms straight from global (L2-hit; off critical path)
    float nw[2][4];
    #pragma unroll
    for (int ot = 0; ot < 2; ++ot)
        #pragma unroll
        for (int rg = 0; rg < 4; ++rg)
            nw[ot][rg] = wn[ob * 32 + 16 * ot + 4 * qp + rg];

    // wave-local stage: bf16 tile [3][192] + sq [192] + P8 partials [24]
    unsigned short* xw = xw_lds[wv];
    float* sqw = sq_lds[wv];
    float* Pw  = P_lds[wv];
    {
        float sx = 0.f, sy = 0.f;
        #pragma unroll
        for (int c = 0; c < 3; ++c) {
            *(unsigned int*)(xw + c * 192 + 2 * lane) = pkbf(va[c].x, va[c].y);
            sx = fmaf(va[c].x, va[c].x, sx);
            sy = fmaf(va[c].y, va[c].y, sy);
        }
        *(float2*)(sqw + 2 * lane) = make_float2(sx, sy);
        float p2 = sx + sy;
        p2 += __shfl_xor(p2, 1, 64);
        p2 += __shfl_xor(p2, 2, 64);
        if ((lane & 3) == 0) Pw[lane >> 2] = p2;          // groups 0..15
        float tx = 0.f, ty = 0.f;
        unsigned int pk[3];
        #pragma unroll
        for (int c = 0; c < 3; ++c) {
            tx = fmaf(vb[c].x, vb[c].x, tx);
            ty = fmaf(vb[c].y, vb[c].y, ty);
            pk[c] = pkbf(vb[c].x, vb[c].y);
        }
        if (lane < 32) {
            #pragma unroll
            for (int c = 0; c < 3; ++c) *(unsigned int*)(xw + c * 192 + 128 + 2 * lane) = pk[c];
            *(float2*)(sqw + 128 + 2 * lane) = make_float2(tx, ty);
        }
        float q2 = tx + ty;
        q2 += __shfl_xor(q2, 1, 64);
        q2 += __shfl_xor(q2, 2, 64);
        if (lane < 32 && (lane & 3) == 0) Pw[16 + (lane >> 2)] = q2;   // groups 16..23
    }

    __syncthreads();   // ONLY barrier: W DMA drained + (own) staging ordered

    // per-lane window half-norms: sum of 8 P partials + 7 incremental updates.
    // Lane owns t = T0w + 8n + r (qp lanes broadcast).
    float wl[8];
    {
        float S = 0.f;
        #pragma unroll
        for (int i = 0; i < 8; ++i) S += Pw[n + i];
        #pragma unroll
        for (int r = 0; r < 8; ++r) {
            wl[r] = (T0w + 8 * n + r < WW) ? 0.5f * S : 1e30f;
            if (r < 7) S += sqw[8 * n + 64 + r] - sqw[8 * n + r];
        }
    }

    // acc init with -(wn + win)
    f32x4 acc[2][8];
    #pragma unroll
    for (int ot = 0; ot < 2; ++ot)
        #pragma unroll
        for (int rg = 0; rg < 4; ++rg)
            #pragma unroll
            for (int r = 0; r < 8; ++r)
                acc[ot][r][rg] = -nw[ot][rg] - wl[r];

    // K-loop: 6 ks x 8 r x 2 ot = 96 MFMAs, no further syncs anywhere
    __builtin_amdgcn_s_setprio(1);
    #pragma unroll
    for (int ks = 0; ks < 6; ++ks) {
        int c = ks >> 1, h = ks & 1;
        int e0b = c * 384 + 64 * h + 16 * (n + qp);
        int4 Ea = *(const int4*)((const char*)xw + e0b);
        int4 Eb = *(const int4*)((const char*)xw + e0b + 16);
        int D[8] = {Ea.x, Ea.y, Ea.z, Ea.w, Eb.x, Eb.y, Eb.z, Eb.w};
        AB a0, a1;
        const int4* wq = (const int4*)w_lds + (ks * 4 + qp) * 32;
        a0.i4 = wq[n];
        a1.i4 = wq[16 + n];
        #pragma unroll
        for (int r = 0; r < 8; ++r) {
            AB bf;
            int s = r >> 1;
            if ((r & 1) == 0) {
                bf.i[0] = D[s]; bf.i[1] = D[s + 1]; bf.i[2] = D[s + 2]; bf.i[3] = D[s + 3];
            } else {
                #pragma unroll
                for (int d = 0; d < 4; ++d)
                    bf.i[d] = (int)__builtin_amdgcn_alignbit((unsigned)D[s + d + 1],
                                                             (unsigned)D[s + d], 16);
            }
            acc[0][r] = __builtin_amdgcn_mfma_f32_16x16x32_bf16(a0.v, bf.v, acc[0][r], 0, 0, 0);
            acc[1][r] = __builtin_amdgcn_mfma_f32_16x16x32_bf16(a1.v, bf.v, acc[1][r], 0, 0, 0);
        }
    }
    __builtin_amdgcn_s_setprio(0);

    // fold over r -> cross-lane max over n -> fused global reduce via atomicMin
    #pragma unroll
    for (int ot = 0; ot < 2; ++ot)
        #pragma unroll
        for (int rg = 0; rg < 4; ++rg) {
            float mm = acc[ot][rg & 3][rg];   // placeholder to keep shape; real fold below
            mm = -FLT_MAX;
            #pragma unroll
            for (int r = 0; r < 8; ++r) mm = fmaxf(mm, acc[ot][r][rg]);
            #pragma unroll
            for (int s = 1; s <= 8; s <<= 1)
                mm = fmaxf(mm, __shfl_xor(mm, s, 64));
            if (n == 0) {
                // -2*mm is a squared distance (>= -bf16 noise): int ordering on
                // float bits is correct for positives; tiny-negative err << tol.
                atomicMin((int*)(out + (size_t)b * OO + ob * 32 + 16 * ot + 4 * qp + rg),
                          __float_as_int(-2.0f * mm));
            }
        }
}

extern "C" void kernel_launch(void* const* d_in, const int* in_sizes, int n_in,
                              void* d_out, int out_size, void* d_ws, size_t ws_size,
                              hipStream_t stream) {
    const float* x = (const float*)d_in[0];   // [32][3][8192]
    const float* w = (const float*)d_in[1];   // [128][3][64]
    float* out = (float*)d_out;               // [32][128]

    // ws: wswz bf16 swizzled [3072 x 16B] (49152 B) | wn f32 [128]
    unsigned short* wswz = (unsigned short*)d_ws;
    float* wn = (float*)((char*)d_ws + 49152);

    prep_kernel<<<29, 256, 0, stream>>>(w, wswz, wn, out);
    dim3 grid(TCX, 4, BB);                    // 2048 blocks, 1 job per wave
    shapeconv_main<<<grid, 256, 0, stream>>>(x, wswz, wn, out);
}

// Round 7
// 73.806 us; speedup vs baseline: 1.0976x; 1.0976x over previous
//
#include <hip/hip_runtime.h>
#include <hip/hip_bf16.h>
#include <float.h>

// x: [B=32][C=3][L=8192] f32, weight: [O=128][C=3][K=64] f32
// out[b][o] = -2 * max_t ( conv(b,o,t) - ||w_o||^2/2 - ||win_{b,t}||^2/2 ), t in [0, 8129)
#define BB 32
#define LL 8192
#define OO 128
#define KK 64
#define WW (LL - KK + 1)   // 8129
#define NCH 4              // 4 chunks x 128 t per wave

typedef __attribute__((ext_vector_type(8))) short short8;
typedef __attribute__((ext_vector_type(4))) float f32x4;

union AB { int4 i4; int i[4]; short8 v; };

static __device__ __forceinline__ unsigned int pkbf(float a, float b) {
    union { __hip_bfloat162 h; unsigned int u; } cv;
    cv.h = __float22bfloat162_rn(make_float2(a, b));   // lo = a, hi = b -> v_cvt_pk_bf16_f32
    return cv.u;
}

// ---- prep: W -> bf16 swizzled [8 ob][24 rr][16 o2] 16B chunks; wn; out-init ----
// chunk (ob, rr=ks*4+qp, o2) holds w[ob*16+o2][c*64+h*32+qp*8 .. +8) bf16, ks=2c+h.
__global__ __launch_bounds__(256) void prep_kernel(const float* __restrict__ w,
                                                   unsigned short* __restrict__ wswz,
                                                   float* __restrict__ wn,
                                                   float* __restrict__ out) {
    int g = blockIdx.x * 256 + threadIdx.x;
    if (g < 3072) {
        int ob = g / 384;
        int rem = g - ob * 384;
        int rr = rem >> 4, o2 = rem & 15;
        int ks = rr >> 2, qp = rr & 3;
        int c = ks >> 1, h = ks & 1;
        const float* p = w + (size_t)(ob * 16 + o2) * 192 + c * 64 + h * 32 + qp * 8;
        float4 v0 = *(const float4*)p, v1 = *(const float4*)(p + 4);
        int4 pk;
        pk.x = (int)pkbf(v0.x, v0.y);
        pk.y = (int)pkbf(v0.z, v0.w);
        pk.z = (int)pkbf(v1.x, v1.y);
        pk.w = (int)pkbf(v1.z, v1.w);
        ((int4*)wswz)[g] = pk;
    }
    int oo = g - 3072;
    if (oo >= 0 && oo < OO) {
        const float* p = w + oo * 192;
        float s = 0.f;
        for (int i = 0; i < 192; ++i) { float v = p[i]; s = fmaf(v, v, s); }
        wn[oo] = 0.5f * s;
    }
    int oi = g - 3200;
    if (oi >= 0 && oi < BB * OO) out[oi] = 3.389e38f;   // +inf-ish for atomicMin
}

// per-wave x slice loads: elements [T0, T0+191] per channel (128 t + 64 halo)
static __device__ __forceinline__ void stage_load(const float* __restrict__ xb, int T0,
                                                  int lane, float2* va, float2* vb) {
    int e0 = T0 + 2 * lane;                  // always < 8192
    #pragma unroll
    for (int c = 0; c < 3; ++c) va[c] = *(const float2*)(xb + c * LL + e0);
    #pragma unroll
    for (int c = 0; c < 3; ++c) vb[c] = make_float2(0.f, 0.f);
    int e1 = T0 + 128 + 2 * lane;            // halo, lanes<32
    if (lane < 32 && e1 < LL) {
        #pragma unroll
        for (int c = 0; c < 3; ++c) vb[c] = *(const float2*)(xb + c * LL + e1);
    }
}

// wave-local store: bf16 tile [3][192] + sq [192] + P8 partials [24]; no barrier
static __device__ __forceinline__ void stage_store(int lane, const float2* va, const float2* vb,
                                                   unsigned short* xw, float* sqw, float* Pw) {
    float sx = 0.f, sy = 0.f;
    #pragma unroll
    for (int c = 0; c < 3; ++c) {
        *(unsigned int*)(xw + c * 192 + 2 * lane) = pkbf(va[c].x, va[c].y);
        sx = fmaf(va[c].x, va[c].x, sx);
        sy = fmaf(va[c].y, va[c].y, sy);
    }
    *(float2*)(sqw + 2 * lane) = make_float2(sx, sy);
    float p2 = sx + sy;
    p2 += __shfl_xor(p2, 1, 64);
    p2 += __shfl_xor(p2, 2, 64);
    if ((lane & 3) == 0) Pw[lane >> 2] = p2;          // groups 0..15
    float tx = 0.f, ty = 0.f;
    unsigned int pk[3];
    #pragma unroll
    for (int c = 0; c < 3; ++c) {
        tx = fmaf(vb[c].x, vb[c].x, tx);
        ty = fmaf(vb[c].y, vb[c].y, ty);
        pk[c] = pkbf(vb[c].x, vb[c].y);
    }
    if (lane < 32) {
        #pragma unroll
        for (int c = 0; c < 3; ++c) *(unsigned int*)(xw + c * 192 + 128 + 2 * lane) = pk[c];
        *(float2*)(sqw + 128 + 2 * lane) = make_float2(tx, ty);
    }
    float q2 = tx + ty;
    q2 += __shfl_xor(q2, 1, 64);
    q2 += __shfl_xor(q2, 2, 64);
    if (lane < 32 && (lane & 3) == 0) Pw[16 + (lane >> 2)] = q2;   // groups 16..23
}

// ---- main: grid (4 tg, 8 ob, 32 b) = 1024 blocks = exactly 4/CU ----
// Wave wv: o in [16ob, 16ob+16), t in [tg*2048 + wv*512, +512), 4 chunks of 128.
// Private x/sq/P LDS dbuf per wave, T14 prefetch, ONE barrier total (W DMA).
__global__ __launch_bounds__(256, 4) void shapeconv_main(const float* __restrict__ x,
                                                         const unsigned short* __restrict__ wswz,
                                                         const float* __restrict__ wn,
                                                         float* __restrict__ out) {
    __shared__ __align__(16) unsigned short w_lds[3072];          // 6144 B (16 o)
    __shared__ __align__(16) unsigned short xw_lds[4][2][576];    // per-wave dbuf bf16 [3][192]
    __shared__ __align__(16) float sq_lds[4][2][192];
    __shared__ __align__(16) float P_lds[4][2][24];

    const int tg = blockIdx.x;
    const int ob = blockIdx.y;     // 0..7 (16 o's per block)
    const int b  = blockIdx.z;
    const int tid = threadIdx.x;
    const int wv = tid >> 6;
    const int lane = tid & 63;
    const int n  = lane & 15;
    const int qp = lane >> 4;
    const int Tw = tg * 2048 + wv * 512;     // wave's t base, <= 7680
    const float* xb = x + (size_t)b * 3 * LL;

    // chunk-0 x loads issue first (latency hides under W DMA + pack)
    float2 va[3], vb[3];
    stage_load(xb, Tw, lane, va, vb);

    // W stage: 6144 B async global->LDS, width 16, linear layout
    {
        const char* src = (const char*)wswz + (size_t)ob * 6144;
        __builtin_amdgcn_global_load_lds(
            (const __attribute__((address_space(1))) unsigned int*)(src + tid * 16),
            (__attribute__((address_space(3))) unsigned int*)((char*)w_lds + tid * 16),
            16, 0, 0);
        if (tid < 128)
            __builtin_amdgcn_global_load_lds(
                (const __attribute__((address_space(1))) unsigned int*)(src + 4096 + tid * 16),
                (__attribute__((address_space(3))) unsigned int*)((char*)w_lds + 4096 + tid * 16),
                16, 0, 0);
    }

    // shapelet half-norms straight from global (L2-hit; off critical path)
    float nw4[4];
    #pragma unroll
    for (int rg = 0; rg < 4; ++rg) nw4[rg] = wn[ob * 16 + 4 * qp + rg];

    unsigned short* xw0 = xw_lds[wv][0];
    float* sq0 = sq_lds[wv][0];
    float* Pw0 = P_lds[wv][0];
    stage_store(lane, va, vb, xw0, sq0, Pw0);

    __syncthreads();   // ONLY barrier: W DMA drained; own staging ordered by lgkmcnt

    float m2[4];
    #pragma unroll
    for (int rg = 0; rg < 4; ++rg) m2[rg] = -FLT_MAX;

    for (int ci = 0; ci < NCH; ++ci) {
        const int bs = ci & 1;
        const int T0 = Tw + ci * 128;
        const bool more = (ci + 1 < NCH);
        if (more) stage_load(xb, T0 + 128, lane, va, vb);   // issue early (T14)

        unsigned short* xw = xw_lds[wv][bs];
        float* sqw = sq_lds[wv][bs];
        float* Pw  = P_lds[wv][bs];

        // per-lane window half-norms: sum of 8 P partials + 7 incremental updates.
        // Lane owns t = T0 + 8n + r (qp lanes broadcast).
        float wl[8];
        {
            float S = 0.f;
            #pragma unroll
            for (int i = 0; i < 8; ++i) S += Pw[n + i];
            #pragma unroll
            for (int r = 0; r < 8; ++r) {
                wl[r] = (T0 + 8 * n + r < WW) ? 0.5f * S : 1e30f;
                if (r < 7) S += sqw[8 * n + 64 + r] - sqw[8 * n + r];
            }
        }

        // acc init with -(wn + win)
        f32x4 acc[8];
        #pragma unroll
        for (int r = 0; r < 8; ++r)
            #pragma unroll
            for (int rg = 0; rg < 4; ++rg)
                acc[r][rg] = -nw4[rg] - wl[r];

        // K-loop: 6 ks x 8 r = 48 MFMAs, wave-local, no syncs
        __builtin_amdgcn_s_setprio(1);
        #pragma unroll
        for (int ks = 0; ks < 6; ++ks) {
            int c = ks >> 1, h = ks & 1;
            int e0b = c * 384 + 64 * h + 16 * (n + qp);
            int4 Ea = *(const int4*)((const char*)xw + e0b);
            int4 Eb = *(const int4*)((const char*)xw + e0b + 16);
            int D[8] = {Ea.x, Ea.y, Ea.z, Ea.w, Eb.x, Eb.y, Eb.z, Eb.w};
            AB a0;
            a0.i4 = ((const int4*)w_lds)[(ks * 4 + qp) * 16 + n];
            #pragma unroll
            for (int r = 0; r < 8; ++r) {
                AB bf;
                int s = r >> 1;
                if ((r & 1) == 0) {
                    bf.i[0] = D[s]; bf.i[1] = D[s + 1]; bf.i[2] = D[s + 2]; bf.i[3] = D[s + 3];
                } else {
                    #pragma unroll
                    for (int d = 0; d < 4; ++d)
                        bf.i[d] = (int)__builtin_amdgcn_alignbit((unsigned)D[s + d + 1],
                                                                 (unsigned)D[s + d], 16);
                }
                acc[r] = __builtin_amdgcn_mfma_f32_16x16x32_bf16(a0.v, bf.v, acc[r], 0, 0, 0);
            }
        }
        __builtin_amdgcn_s_setprio(0);

        // per-chunk register max
        #pragma unroll
        for (int rg = 0; rg < 4; ++rg) {
            float mm = m2[rg];
            #pragma unroll
            for (int r = 0; r < 8; ++r) mm = fmaxf(mm, acc[r][rg]);
            m2[rg] = mm;
        }

        if (more)   // write late: loads issued pre-K-loop retired long ago
            stage_store(lane, va, vb, xw_lds[wv][1 - bs], sq_lds[wv][1 - bs], P_lds[wv][1 - bs]);
    }

    // cross-lane max over n -> fused global reduce via atomicMin (values >= -eps)
    #pragma unroll
    for (int rg = 0; rg < 4; ++rg) {
        float mm = m2[rg];
        #pragma unroll
        for (int s = 1; s <= 8; s <<= 1)
            mm = fmaxf(mm, __shfl_xor(mm, s, 64));
        if (n == 0) {
            // -2*mm is a squared distance (>= -bf16 noise): int ordering on float
            // bits is correct for non-negatives; tiny-negative err << tolerance.
            atomicMin((int*)(out + (size_t)b * OO + ob * 16 + 4 * qp + rg),
                      __float_as_int(-2.0f * mm));
        }
    }
}

extern "C" void kernel_launch(void* const* d_in, const int* in_sizes, int n_in,
                              void* d_out, int out_size, void* d_ws, size_t ws_size,
                              hipStream_t stream) {
    const float* x = (const float*)d_in[0];   // [32][3][8192]
    const float* w = (const float*)d_in[1];   // [128][3][64]
    float* out = (float*)d_out;               // [32][128]

    // ws: wswz bf16 swizzled [3072 x 16B] (49152 B) | wn f32 [128]
    unsigned short* wswz = (unsigned short*)d_ws;
    float* wn = (float*)((char*)d_ws + 49152);

    prep_kernel<<<29, 256, 0, stream>>>(w, wswz, wn, out);
    dim3 grid(4, 8, BB);                      // 1024 blocks = 4/CU, single round
    shapeconv_main<<<grid, 256, 0, stream>>>(x, wswz, wn, out);
}